// Round 13
// baseline (334.792 us; speedup 1.0000x reference)
//
#include <hip/hip_runtime.h>
#include <hip/hip_bf16.h>
#include <math.h>

// ---------- types ----------
typedef __attribute__((ext_vector_type(8))) __bf16 bf16x8;
typedef __attribute__((ext_vector_type(4))) float f32x4;

// fp32 -> bf16 round-to-nearest-even
__device__ __forceinline__ unsigned short f2bf(float f) {
    union { float f; unsigned u; } v; v.f = f;
    unsigned r = v.u + 0x7fffu + ((v.u >> 16) & 1u);
    return (unsigned short)(r >> 16);
}
// pack two fp32 into one dword of two bf16 (lo, hi)
__device__ __forceinline__ unsigned int pk(float a, float b) {
    union { float f; unsigned u; } x, y; x.f = a; y.f = b;
    unsigned ra = (x.u + 0x7fffu + ((x.u >> 16) & 1u)) >> 16;
    unsigned rb = (y.u + 0x7fffu + ((y.u >> 16) & 1u)) & 0xffff0000u;
    return ra | rb;
}

// ---------- wprep kernel: weight transform + leftover copies ----------
// blocks [0,448): convert W to MFMA FRAGMENT ORDER (round-8 layout):
//   WTf[kt][cg][lane][e]; B load in GEMM = base + lane*16, coalesced 1 KB.
// blocks [448, 448+4096): leftover passthrough copies (moved here from the
// fused kernel, round-11 lesson: they were capped at 2 blocks/CU by fused's
// 72 KB LDS and serialized as a low-occupancy tail; here LDS=17 KB).
struct WArgs {
    const float* fv;
    const int *not_idx, *leftover;
    float* out;
    const float* W[5];
    unsigned short* WT[5];
    int N[5];
    int tstart[6];
};

__global__ __launch_bounds__(256) void wprep_kernel(WArgs a) {
    __shared__ float tile[64][65];
    const int blk = blockIdx.x;
    const int tid = threadIdx.x;

    if (blk >= 448) {
        // copy blocks: one wave = one (b,ls) row of 512 floats
        const int t = (blk - 448) * 256 + tid;           // 8 floats each
        const size_t e = (size_t)t * 8;
        const int c  = (int)(e & 511);
        const int ls = (int)((e >> 9) & 15);
        const int b  = (int)(e >> 13);
        const int f  = a.leftover[ls];                   // wave-uniform
        int isnot = 0;
        #pragma unroll
        for (int i = 0; i < 8; i++) isnot |= (a.not_idx[i] == f);
        if (isnot) return;                               // tanh path writes
        const float* s = a.fv + ((size_t)b * 64 + f) * 512 + c;
        float* d = a.out + ((size_t)b * 40 + 24 + ls) * 512 + c;
        *(float4*)(d)     = *(const float4*)(s);
        *(float4*)(d + 4) = *(const float4*)(s + 4);
        return;
    }

    int m = 0;
    while (blk >= a.tstart[m + 1]) m++;
    const float* src = a.W[m];
    unsigned short* dst = a.WT[m];
    const int N = a.N[m];
    const int t = blk - a.tstart[m];
    const int ntn = N >> 6;
    const int tk = t / ntn, tn = t % ntn;
    const int c = tid & 63, r0 = tid >> 6;
    #pragma unroll
    for (int r = r0; r < 64; r += 4)
        tile[r][c] = src[(size_t)(tk * 64 + r) * N + tn * 64 + c];
    __syncthreads();
    const int l = tid & 63;
    #pragma unroll
    for (int fi = tid >> 6; fi < 8; fi += 4) {
        const int ktl = fi & 1, cgl = fi >> 1;
        const int kt = tk * 2 + ktl, cg = tn * 4 + cgl;
        const int kb = ktl * 32 + (l >> 4) * 8;
        const int nb = cgl * 16 + (l & 15);
        uint4 o;
        o.x = pk(tile[kb + 0][nb], tile[kb + 1][nb]);
        o.y = pk(tile[kb + 2][nb], tile[kb + 3][nb]);
        o.z = pk(tile[kb + 4][nb], tile[kb + 5][nb]);
        o.w = pk(tile[kb + 6][nb], tile[kb + 7][nb]);
        ((uint4*)dst)[((size_t)kt * 32 + cg) * 64 + l] = o;
    }
}

// ---------- fused two-layer GEMM, A DIRECT FROM fv ----------
// Block: BM=64 rows x ALL 512 cols, 8 waves, wave owns 64 cols: acc[4][4].
// A: reg-staged direct from fv (fp32 float4 -> pk -> ds_write, chunk-XOR
//    swizzled), 2 LDS buffers.  A reg-pipeline 4 steps deep (v0..v3,
//    4x-unrolled loop for static reg naming, rule 20) -- each load has
//    >=3 steps (~1500 cyc) before its ds_write, covering cold-HBM fv.
// B: fragment-ordered coalesced 1-KB loads, REGISTER DOUBLE-BUFFERED --
//    LOADB(h+1) issues a full step before MMAC(h+1), hiding the ~300cyc
//    L2 latency that was serialized every step in rounds 9-11.
// All VMEM reg-destined -> compiler tracks waits.  Per-step sync:
// s_waitcnt lgkmcnt(0); s_barrier.
//   RAW: my ds_writes for buf X at step h are lgkm-drained before barrier
//     h+1; readers read X at h+1 after that barrier.
//   WAR: my ds_write to buf (h+1)&1 at step h happens after barrier h;
//     other waves' reads of that buffer (step h-1) completed before their
//     MMAC(h-1) lgkm-wait, which precedes their barrier-h arrival.
// hid LDS [64][512] bf16, 16B-chunk XOR swizzle -> L2-stage reads 2-way max.
// PATH 0: relu->hid(LDS)->L2->out fp32 (+bias), rows m=b*P+p, q=QBASE+p
// PATH 2: single layer, tanh->out, rows m=b*8+i, q=qmap[i]
#define LOADB(DST, WTP, K0)                                                  \
    _Pragma("unroll") for (int ni = 0; ni < 4; ni++)                         \
        DST[ni] = *(const bf16x8*)((WTP) +                                   \
            ((((size_t)(K0) >> 5) * 32 + cg0 + ni) << 9) + (lane << 3));

#define MMAC(BF, AF)                                                         \
    _Pragma("unroll") for (int mi = 0; mi < 4; mi++)                         \
    _Pragma("unroll") for (int ni = 0; ni < 4; ni++)                         \
        acc[mi][ni] = __builtin_amdgcn_mfma_f32_16x16x32_bf16(               \
            AF[mi], BF[ni], acc[mi][ni], 0, 0, 0);

#define LBAR()                                                               \
    asm volatile("s_waitcnt lgkmcnt(0)" ::: "memory");                       \
    asm volatile("s_barrier" ::: "memory");

#define AFRD(AF, BUF)                                                        \
    _Pragma("unroll") for (int mi = 0; mi < 4; mi++)                         \
        AF[mi] = *(const bf16x8*)&As[(BUF) * 2048 +                          \
                                     (mi * 16 + ln15) * 32 + xsel];

template <int P, int K1, int PATH, int QBASE>
__device__ __forceinline__ void fused_seg(
    const float* __restrict__ fv,
    const int* __restrict__ idx,
    const unsigned short* __restrict__ W1T,
    const float* __restrict__ b1,
    const unsigned short* __restrict__ W2T,
    const float* __restrict__ b2,
    float* __restrict__ out,
    const int* __restrict__ leftover,
    int local,
    unsigned short* As, unsigned short* hid) {

    const int tid  = threadIdx.x;
    const int lane = tid & 63, w = tid >> 6;      // 8 waves
    const int ln15 = lane & 15;
    const int kq   = lane >> 4;                   // k-chunk quad 0..3
    const int wn   = w * 64;                      // wave's col base
    const int cg0  = w * 4;                       // wave's col-group base
    const int m0   = local * 64;                  // block's row base
    constexpr int NTK = K1 / 32;                  // 16 or 32 (mult of 4)

    // --- A staging geometry: thread covers row r, k-segment ks (4 floats)
    const int r  = tid >> 3;                      // 0..63
    const int ks = tid & 7;                       // 0..7
    const float *ar0, *ar1;
    {
        const int m = m0 + r;
        if constexpr (PATH == 0) {
            const int b = m / P, p = m % P;
            ar0 = fv + ((size_t)b * 64 + idx[2 * p]) * 512 + ks * 4;
            ar1 = fv + ((size_t)b * 64 + idx[2 * p + 1]) * 512 + ks * 4;
        } else {
            const int b = m >> 3, i = m & 7;
            ar0 = fv + ((size_t)b * 64 + idx[i]) * 512 + ks * 4;
            ar1 = ar0;
        }
    }
    auto ldA = [&](int t) -> float4 {
        const int k0 = t * 32;
        if constexpr (K1 == 1024)
            return *(const float4*)(k0 >= 512 ? ar1 + (k0 - 512) : ar0 + k0);
        else
            return *(const float4*)(ar0 + k0);
    };
    // ds_write dest (shorts): row r, chunk slot (ks>>1)^(r&3), half ks&1
    unsigned short* const wdst =
        As + r * 32 + (((ks >> 1) ^ (r & 3)) << 3) + ((ks & 1) << 2);
    auto wrA = [&](int buf, float4 v) {
        uint2 o; o.x = pk(v.x, v.y); o.y = pk(v.z, v.w);
        *(uint2*)(wdst + buf * 2048) = o;
    };
    const int xsel = (kq ^ (lane & 3)) * 8;       // frag-read chunk slot

    f32x4 acc[4][4];
    #pragma unroll
    for (int mi = 0; mi < 4; mi++)
        #pragma unroll
        for (int ni = 0; ni < 4; ni++)
            acc[mi][ni] = f32x4{0.f, 0.f, 0.f, 0.f};

    bf16x8 bA[4], bB[4];

    // ---- L1: acc = A[64,K1] @ W1[K1,512] ----
    // 4-deep A regs (v0..v3), 2 LDS bufs, B reg-dbuf (bA/bB).
    float4 v0 = ldA(0), v1 = ldA(1), v2 = ldA(2), v3 = ldA(3);
    LOADB(bA, W1T, 0);
    wrA(0, v0);
    LBAR();                         // buf0 visible

    for (int h = 0; h < NTK; h += 4) {
        bf16x8 af[4];
        // s0: read buf0=A(h), B=bA; prefetch bB(h+1), v0<-A(h+4); wr buf1<-v1
        LOADB(bB, W1T, (h + 1) * 32);
        if (h + 4 < NTK) v0 = ldA(h + 4);
        AFRD(af, 0);
        MMAC(bA, af);
        wrA(1, v1);
        LBAR();
        // s1: read buf1=A(h+1), B=bB; prefetch bA(h+2), v1<-A(h+5); wr buf0<-v2
        LOADB(bA, W1T, (h + 2) * 32);
        if (h + 5 < NTK) v1 = ldA(h + 5);
        AFRD(af, 1);
        MMAC(bB, af);
        wrA(0, v2);
        LBAR();
        // s2: read buf0=A(h+2), B=bA; prefetch bB(h+3), v2<-A(h+6); wr buf1<-v3
        LOADB(bB, W1T, (h + 3) * 32);
        if (h + 6 < NTK) v2 = ldA(h + 6);
        AFRD(af, 0);
        MMAC(bA, af);
        wrA(1, v3);
        LBAR();
        // s3: read buf1=A(h+3), B=bB; prefetch bA(h+4), v3<-A(h+7); wr buf0<-v0
        if (h + 4 < NTK) { LOADB(bA, W1T, (h + 4) * 32); }
        if (h + 7 < NTK) v3 = ldA(h + 7);
        AFRD(af, 1);
        MMAC(bB, af);
        if (h + 4 < NTK) { wrA(0, v0); }
        LBAR();
    }

    if constexpr (PATH == 2) {
        // single layer: tanh -> out at leftover slot
        int qmap[8];
        #pragma unroll
        for (int i = 0; i < 8; i++) {
            const int f = idx[i];
            int q = 24;
            for (int l = 0; l < 16; l++)
                if (leftover[l] == f) q = 24 + l;
            qmap[i] = q;
        }
        #pragma unroll
        for (int ni = 0; ni < 4; ni++) {
            const int n = wn + ni * 16 + ln15;
            const float bv = b1[n];
            #pragma unroll
            for (int mi = 0; mi < 4; mi++)
                #pragma unroll
                for (int j = 0; j < 4; j++) {
                    const int rr = mi * 16 + kq * 4 + j;
                    const int m = m0 + rr;
                    const int b = m >> 3, i = m & 7;
                    out[((size_t)b * 40 + qmap[i]) * 512 + n] =
                        tanhf(acc[mi][ni][j] + bv);
                }
        }
        return;
    }

    // ---- L1 epilogue: relu -> bf16 -> hid LDS (XOR-swizzled chunks) ----
    #pragma unroll
    for (int ni = 0; ni < 4; ni++) {
        const int n  = wn + ni * 16 + ln15;
        const float bv = b1[n];
        const int c8 = n >> 3;
        const int cl = (n & 7) * 2;
        #pragma unroll
        for (int mi = 0; mi < 4; mi++)
            #pragma unroll
            for (int j = 0; j < 4; j++) {
                const int rr = mi * 16 + kq * 4 + j;
                float v = acc[mi][ni][j] + bv;
                v = v > 0.f ? v : 0.f;
                *(unsigned short*)((char*)hid + rr * 1024 +
                                   ((c8 ^ (rr & 7)) * 16) + cl) = f2bf(v);
            }
    }
    #pragma unroll
    for (int mi = 0; mi < 4; mi++)
        #pragma unroll
        for (int ni = 0; ni < 4; ni++)
            acc[mi][ni] = f32x4{0.f, 0.f, 0.f, 0.f};
    __syncthreads();                       // hid visible

    // ---- L2: acc = hid[64,512] @ W2[512,512], A from LDS, B reg-dbuf ----
    LOADB(bA, W2T, 0);
    for (int t2 = 0; t2 < 16; t2 += 2) {
        bf16x8 af[4];
        LOADB(bB, W2T, (t2 + 1) * 32);
        #pragma unroll
        for (int mi = 0; mi < 4; mi++) {
            const int rr = mi * 16 + ln15;
            const int c8 = t2 * 4 + kq;
            af[mi] = *(const bf16x8*)((char*)hid + rr * 1024 +
                                      ((c8 ^ (rr & 7)) * 16));
        }
        MMAC(bA, af);
        if (t2 + 2 < 16) { LOADB(bA, W2T, (t2 + 2) * 32); }
        #pragma unroll
        for (int mi = 0; mi < 4; mi++) {
            const int rr = mi * 16 + ln15;
            const int c8 = (t2 + 1) * 4 + kq;
            af[mi] = *(const bf16x8*)((char*)hid + rr * 1024 +
                                      ((c8 ^ (rr & 7)) * 16));
        }
        MMAC(bB, af);
    }

    // ---- L2 epilogue: +bias -> fp32 out ----
    #pragma unroll
    for (int ni = 0; ni < 4; ni++) {
        const int n  = wn + ni * 16 + ln15;
        const float bv = b2[n];
        #pragma unroll
        for (int mi = 0; mi < 4; mi++)
            #pragma unroll
            for (int j = 0; j < 4; j++) {
                const int rr = mi * 16 + kq * 4 + j;
                const int m = m0 + rr;
                const int b = m / P, p = m % P;    // P constexpr -> shifts
                out[((size_t)b * 40 + QBASE + p) * 512 + n] =
                    acc[mi][ni][j] + bv;
            }
    }
}

// ---------- fused phase kernel ----------
struct FArgs {
    const float* fv;
    const unsigned short *and_W1T, *and_W2T, *or_W1T, *or_W2T, *not_WT;
    const int *and_pairs, *or_pairs, *not_idx, *leftover;
    const float *and_b1, *and_b2, *or_b1, *or_b2, *not_b;
    float* out;
};

__global__ __launch_bounds__(512, 4) void fused_phase(FArgs a) {
    __shared__ __align__(16) unsigned short As[2 * 64 * 32];   // 8 KB, 2 bufs
    __shared__ __align__(16) unsigned short hid[64 * 512];     // 64 KB
    const int blk = blockIdx.x;
    if (blk < 256) {      // and: M=16384 -> 256 blocks of 64 rows
        fused_seg<16, 1024, 0, 0>(a.fv, a.and_pairs, a.and_W1T, a.and_b1,
                                  a.and_W2T, a.and_b2, a.out, nullptr,
                                  blk, As, hid);
    } else if (blk < 384) { // or: M=8192 -> 128 blocks
        fused_seg<8, 1024, 0, 16>(a.fv, a.or_pairs, a.or_W1T, a.or_b1,
                                  a.or_W2T, a.or_b2, a.out, nullptr,
                                  blk - 256, As, hid);
    } else {              // not: M=8192, single layer tanh -> 128 blocks
        fused_seg<8, 512, 2, 24>(a.fv, a.not_idx, a.not_WT, a.not_b,
                                 nullptr, nullptr, a.out, a.leftover,
                                 blk - 384, As, hid);
    }
}

// ---------- launch ----------
extern "C" void kernel_launch(void* const* d_in, const int* in_sizes, int n_in,
                              void* d_out, int out_size, void* d_ws, size_t ws_size,
                              hipStream_t stream) {
    const float* fv       = (const float*)d_in[0];
    const float* and_W1   = (const float*)d_in[1];
    const float* and_b1   = (const float*)d_in[2];
    const float* and_W2   = (const float*)d_in[3];
    const float* and_b2   = (const float*)d_in[4];
    const float* or_W1    = (const float*)d_in[5];
    const float* or_b1    = (const float*)d_in[6];
    const float* or_W2    = (const float*)d_in[7];
    const float* or_b2    = (const float*)d_in[8];
    const float* not_W    = (const float*)d_in[9];
    const float* not_b    = (const float*)d_in[10];
    const int* not_idx    = (const int*)d_in[11];
    const int* and_pairs  = (const int*)d_in[12];
    const int* or_pairs   = (const int*)d_in[13];
    const int* leftover   = (const int*)d_in[14];
    float* out = (float*)d_out;
    char* ws = (char*)d_ws;

    // ws layout (bytes) -- weights only
    unsigned short* and_W1T = (unsigned short*)(ws);              // 1 MB
    unsigned short* or_W1T  = (unsigned short*)(ws + 1048576);    // 1 MB
    unsigned short* and_W2T = (unsigned short*)(ws + 2097152);    // 0.5 MB
    unsigned short* or_W2T  = (unsigned short*)(ws + 2621440);    // 0.5 MB
    unsigned short* not_WT  = (unsigned short*)(ws + 3145728);    // 0.5 MB

    WArgs wa;
    wa.fv = fv; wa.out = out;
    wa.not_idx = not_idx; wa.leftover = leftover;
    wa.W[0] = and_W1; wa.WT[0] = and_W1T; wa.N[0] = 512;
    wa.W[1] = or_W1;  wa.WT[1] = or_W1T;  wa.N[1] = 512;
    wa.W[2] = and_W2; wa.WT[2] = and_W2T; wa.N[2] = 512;
    wa.W[3] = or_W2;  wa.WT[3] = or_W2T;  wa.N[3] = 512;
    wa.W[4] = not_W;  wa.WT[4] = not_WT;  wa.N[4] = 512;
    wa.tstart[0] = 0;   wa.tstart[1] = 128; wa.tstart[2] = 256;
    wa.tstart[3] = 320; wa.tstart[4] = 384; wa.tstart[5] = 448;
    // 448 weight blocks + 4096 leftover-copy blocks
    wprep_kernel<<<dim3(448 + 4096), dim3(256), 0, stream>>>(wa);

    FArgs fa;
    fa.fv = fv;
    fa.and_W1T = and_W1T; fa.and_W2T = and_W2T;
    fa.or_W1T = or_W1T;   fa.or_W2T = or_W2T;   fa.not_WT = not_WT;
    fa.and_pairs = and_pairs; fa.or_pairs = or_pairs; fa.not_idx = not_idx;
    fa.leftover = leftover;
    fa.and_b1 = and_b1; fa.and_b2 = and_b2;
    fa.or_b1 = or_b1;   fa.or_b2 = or_b2;   fa.not_b = not_b;
    fa.out = out;
    fused_phase<<<dim3(512), dim3(512), 0, stream>>>(fa);
}

// Round 14
// 298.971 us; speedup vs baseline: 1.1198x; 1.1198x over previous
//
#include <hip/hip_runtime.h>
#include <hip/hip_bf16.h>
#include <math.h>

// ---------- types ----------
typedef __attribute__((ext_vector_type(8))) __bf16 bf16x8;
typedef __attribute__((ext_vector_type(4))) float f32x4;

// fp32 -> bf16 round-to-nearest-even
__device__ __forceinline__ unsigned short f2bf(float f) {
    union { float f; unsigned u; } v; v.f = f;
    unsigned r = v.u + 0x7fffu + ((v.u >> 16) & 1u);
    return (unsigned short)(r >> 16);
}
// pack two fp32 into one dword of two bf16 (lo, hi)
__device__ __forceinline__ unsigned int pk(float a, float b) {
    union { float f; unsigned u; } x, y; x.f = a; y.f = b;
    unsigned ra = (x.u + 0x7fffu + ((x.u >> 16) & 1u)) >> 16;
    unsigned rb = (y.u + 0x7fffu + ((y.u >> 16) & 1u)) & 0xffff0000u;
    return ra | rb;
}

// async global->LDS, 16 B per lane; LDS dest = wave-uniform base + lane*16
__device__ __forceinline__ void gl2lds16(const unsigned short* g, unsigned short* l) {
    __builtin_amdgcn_global_load_lds(
        (const __attribute__((address_space(1))) unsigned int*)(g),
        (__attribute__((address_space(3))) unsigned int*)(l), 16, 0, 0);
}

// ---------- prep kernel (round-10 structure, best measured: 298.7us) ----
// blocks [0,448): weight convert to MFMA FRAGMENT ORDER (round-8 layout):
//   WTf[kt][cg][lane][e]; B load in GEMM = base + lane*16, coalesced 1 KB.
// blocks [448, 448+16384): fv streaming.  One wave = one field row; ballots
// give the wave-uniform consumer.  Writes PRE-GATHERED, K-TILED,
// DMA-ORDERED A matrices (round-9 lesson: A-gather belongs on prep's
// store side, not fused's latency-critical load path).  Layout:
// At[mt][kt][sub][lane][16B]: 16 B at lane l of subtile sub holds row
// r = sub*16 + (l>>2), k-chunk kc = (l&3) ^ (r&3) (swizzle baked in).
struct PrepArgs {
    const float* fv;
    unsigned short *and_At, *or_At, *not_At;
    const int *and_pairs, *or_pairs, *not_idx, *lidx;
    float* out;
    const float* W[5];
    unsigned short* WT[5];
    int N[5];
    int tstart[6];
};

__global__ __launch_bounds__(256) void prep_kernel(PrepArgs a) {
    __shared__ float tile[64][65];
    const int blk = blockIdx.x;
    const int tid = threadIdx.x;

    if (blk < 448) {
        int m = 0;
        while (blk >= a.tstart[m + 1]) m++;
        const float* src = a.W[m];
        unsigned short* dst = a.WT[m];
        const int N = a.N[m];
        const int t = blk - a.tstart[m];
        const int ntn = N >> 6;
        const int tk = t / ntn, tn = t % ntn;
        const int c = tid & 63, r0 = tid >> 6;
        #pragma unroll
        for (int r = r0; r < 64; r += 4)
            tile[r][c] = src[(size_t)(tk * 64 + r) * N + tn * 64 + c];
        __syncthreads();
        const int l = tid & 63;
        #pragma unroll
        for (int fi = tid >> 6; fi < 8; fi += 4) {
            const int ktl = fi & 1, cgl = fi >> 1;
            const int kt = tk * 2 + ktl, cg = tn * 4 + cgl;
            const int kb = ktl * 32 + (l >> 4) * 8;
            const int nb = cgl * 16 + (l & 15);
            uint4 o;
            o.x = pk(tile[kb + 0][nb], tile[kb + 1][nb]);
            o.y = pk(tile[kb + 2][nb], tile[kb + 3][nb]);
            o.z = pk(tile[kb + 4][nb], tile[kb + 5][nb]);
            o.w = pk(tile[kb + 6][nb], tile[kb + 7][nb]);
            ((uint4*)dst)[((size_t)kt * 32 + cg) * 64 + l] = o;
        }
        return;
    }

    const int t = (blk - 448) * 256 + tid;   // 8 consecutive floats
    const int lane = tid & 63;               // == 16B-chunk index c8 of the row
    const size_t e = (size_t)t * 8;
    const int c = (int)(e & 511);
    const int f = (int)((e >> 9) & 63);
    const int b = (int)(e >> 15);
    const float4 v0 = *(const float4*)(a.fv + e);
    const float4 v1 = *(const float4*)(a.fv + e + 4);
    const int am = (lane < 32) ? a.and_pairs[lane] : -1;
    const int om = (lane < 16) ? a.or_pairs[lane]  : -1;
    const int nm = (lane <  8) ? a.not_idx[lane]   : -1;
    const int lm = (lane < 16) ? a.lidx[lane]      : -1;
    const unsigned long long ba = __ballot(am == f);
    const unsigned long long bo = __ballot(om == f);
    const unsigned long long bn = __ballot(nm == f);
    const unsigned long long bl = __ballot(lm == f);

    uint4 o;
    o.x = pk(v0.x, v0.y); o.y = pk(v0.z, v0.w);
    o.z = pk(v1.x, v1.y); o.w = pk(v1.z, v1.w);
    const int c8 = lane;
    const int kc = c8 & 3;                   // chunk within a 32-k tile

    if (ba) {                                // and: m = b*16+p, k += s*512
        const int j = (int)__builtin_ctzll(ba);
        const int m = b * 16 + (j >> 1);
        const int kt = (j & 1) * 16 + (c8 >> 2);          // NTK=32
        const int r = m & 63;
        const int l = ((r & 15) << 2) | (kc ^ (r & 3));
        *(uint4*)(a.and_At +
            (((((size_t)(m >> 6) * 32 + kt) << 2) | (unsigned)(r >> 4)) << 9) +
            (l << 3)) = o;
    }
    if (bo) {                                // or: m = b*8+p
        const int j = (int)__builtin_ctzll(bo);
        const int m = b * 8 + (j >> 1);
        const int kt = (j & 1) * 16 + (c8 >> 2);          // NTK=32
        const int r = m & 63;
        const int l = ((r & 15) << 2) | (kc ^ (r & 3));
        *(uint4*)(a.or_At +
            (((((size_t)(m >> 6) * 32 + kt) << 2) | (unsigned)(r >> 4)) << 9) +
            (l << 3)) = o;
    }
    if (bn) {                                // not: m = b*8+i, K=512
        const int i = (int)__builtin_ctzll(bn);
        const int m = b * 8 + i;
        const int kt = c8 >> 2;                           // NTK=16
        const int r = m & 63;
        const int l = ((r & 15) << 2) | (kc ^ (r & 3));
        *(uint4*)(a.not_At +
            (((((size_t)(m >> 6) * 16 + kt) << 2) | (unsigned)(r >> 4)) << 9) +
            (l << 3)) = o;
    }
    if (bl && !bn) {   // leftover passthrough (not-fields written by tanh GEMM)
        const int ls = (int)__builtin_ctzll(bl);
        float* d = a.out + ((size_t)b * 40 + 24 + ls) * 512 + c;
        *(float4*)(d)     = v0;
        *(float4*)(d + 4) = v1;
    }
}

// ---------- fused two-layer GEMM segment ----------
// ROUND-14: round-10 base (best measured) + ONE change: B register
// double-buffer.  Round-13 lesson: B-dbuf(+16) + 4-deep A regs(+8) spilled
// (traffic +46 MB); here A stays DMA-staged (register-light) so
// acc 64 + bA 16 + bB 16 + af 16 ~= 112 + addr fits the 128 bucket.
// A: pre-gathered k-tiled At -> stageA = ONE contiguous 1 KB gl2lds per
//    staging wave (waves 0..3), 4 buffers, staged 2 ahead.
// B: fragment-ordered, 4 coalesced 1-KB flat loads, loaded ONE STEP AHEAD
//    (bA/bB alternate, 2x-unrolled loop) -- hides B's ~300cyc L2 latency
//    that r9-r11 serialized into every step.
// Sync per step: s_waitcnt vmcnt(4) lgkmcnt(0); s_barrier.
//   Staging-wave outstanding at barrier h (oldest first):
//     h=0:        [A0, A1, B0x4]          vmcnt(4) retires A0 (and A1)
//     steady h:   [A(h), B(h)x4, A(h+1)]  vmcnt(4) retires A(h)+B(h)#1
//     h=NTK-1:    [A(h), B(h)x4]          vmcnt(4) retires A(h)
//   (B(h) is consumed THIS step right after, so retiring part of it is
//   free; A(h+1) stays in flight.)  Non-staging waves: [B(h)x4] no-op;
//   their A-visibility comes from the barrier (staging waves prove their
//   A(h) part BEFORE arriving).  WAR on the 4 A-bufs: readers of buf
//   (h+2)&3 ran at step h-2 and lgkm-retired before barrier h-1.
// hid LDS [64][512] bf16, 16B-chunk XOR swizzle -> L2-stage reads 2-way max.
// PATH 0: relu->hid(LDS)->L2->out fp32 (+bias), rows m=b*P+p, q=QBASE+p
// PATH 2: single layer, tanh->out, rows m=b*8+i, q=qmap[i]
#define LOADB(DST, WTP, K0)                                                  \
    _Pragma("unroll") for (int ni = 0; ni < 4; ni++)                         \
        DST[ni] = *(const bf16x8*)((WTP) +                                   \
            ((((size_t)(K0) >> 5) * 32 + cg0 + ni) << 9) + (lane << 3));

#define MMAC(BF, AF)                                                         \
    _Pragma("unroll") for (int mi = 0; mi < 4; mi++)                         \
    _Pragma("unroll") for (int ni = 0; ni < 4; ni++)                         \
        acc[mi][ni] = __builtin_amdgcn_mfma_f32_16x16x32_bf16(               \
            AF[mi], BF[ni], acc[mi][ni], 0, 0, 0);

#define AFRD(AF, BUF)                                                        \
    _Pragma("unroll") for (int mi = 0; mi < 4; mi++)                         \
        AF[mi] = *(const bf16x8*)&As[(BUF) * 2048 +                          \
                                     (mi * 16 + ln15) * 32 + xsel];

#define FBAR()                                                               \
    asm volatile("s_waitcnt vmcnt(4) lgkmcnt(0)" ::: "memory");              \
    asm volatile("s_barrier" ::: "memory");

template <int P, int K1, int PATH, int QBASE>
__device__ __forceinline__ void fused_seg(
    const unsigned short* __restrict__ At,
    const unsigned short* __restrict__ W1T,
    const float* __restrict__ b1,
    const unsigned short* __restrict__ W2T,
    const float* __restrict__ b2,
    float* __restrict__ out,
    const int* __restrict__ nidx,
    const int* __restrict__ leftover,
    int local,
    unsigned short* As, unsigned short* hid) {

    const int tid  = threadIdx.x;
    const int lane = tid & 63, w = tid >> 6;      // 8 waves
    const int ln15 = lane & 15;
    const int kq   = lane >> 4;                   // k-chunk quad 0..3
    const int wn   = w * 64;                      // wave's col base
    const int cg0  = w * 4;                       // wave's col-group base
    const int m0   = local * 64;                  // block's row base
    constexpr int NTK = K1 / 32;                  // 32 or 16 (even)

    // A source: fully linear DMA stream (pre-gathered by prep)
    const unsigned short* abase =
        At + (size_t)local * NTK * 2048 + ((w & 3) << 9) + (lane << 3);
    auto stageA = [&](int buf, int t) {
        gl2lds16(abase + (size_t)t * 2048, &As[buf * 2048 + (w & 3) * 512]);
    };
    const int xsel = (kq ^ (lane & 3)) * 8;   // frag-read chunk slot

    f32x4 acc[4][4];
    #pragma unroll
    for (int mi = 0; mi < 4; mi++)
        #pragma unroll
        for (int ni = 0; ni < 4; ni++)
            acc[mi][ni] = f32x4{0.f, 0.f, 0.f, 0.f};

    bf16x8 bA[4], bB[4];

    // ---- L1: acc = A[64,K1] @ W1[K1,512] ----
    if (w < 4) { stageA(0, 0); stageA(1, 1); }
    __builtin_amdgcn_sched_barrier(0);
    LOADB(bA, W1T, 0);                           // B(0), one step of flight

    for (int h = 0; h < NTK; h += 2) {
        bf16x8 af[4];
        // even step: consume bA = B(h), buf h&3
        FBAR();                                      // A(h) proven landed
        if (h + 1 < NTK) { LOADB(bB, W1T, (h + 1) * 32); }   // prefetch B(h+1)
        __builtin_amdgcn_sched_barrier(0);           // pin B before A-stage
        if (w < 4 && h + 2 < NTK) stageA((h + 2) & 3, h + 2);
        __builtin_amdgcn_sched_barrier(0);
        AFRD(af, h & 3);
        MMAC(bA, af);                                // waits B(h)
        __builtin_amdgcn_sched_barrier(0);
        // odd step: consume bB = B(h+1), buf (h+1)&3
        FBAR();                                      // A(h+1) proven landed
        if (h + 2 < NTK) { LOADB(bA, W1T, (h + 2) * 32); }   // prefetch B(h+2)
        __builtin_amdgcn_sched_barrier(0);           // pin B before A-stage
        if (w < 4 && h + 3 < NTK) stageA((h + 3) & 3, h + 3);
        __builtin_amdgcn_sched_barrier(0);
        AFRD(af, (h + 1) & 3);
        MMAC(bB, af);                                // waits B(h+1)
        __builtin_amdgcn_sched_barrier(0);
    }

    if constexpr (PATH == 2) {
        // single layer: tanh -> out at leftover slot
        int qmap[8];
        #pragma unroll
        for (int i = 0; i < 8; i++) {
            const int f = nidx[i];
            int q = 24;
            for (int l = 0; l < 16; l++)
                if (leftover[l] == f) q = 24 + l;
            qmap[i] = q;
        }
        #pragma unroll
        for (int ni = 0; ni < 4; ni++) {
            const int n = wn + ni * 16 + ln15;
            const float bv = b1[n];
            #pragma unroll
            for (int mi = 0; mi < 4; mi++)
                #pragma unroll
                for (int j = 0; j < 4; j++) {
                    const int r = mi * 16 + kq * 4 + j;
                    const int m = m0 + r;
                    const int b = m >> 3, i = m & 7;
                    out[((size_t)b * 40 + qmap[i]) * 512 + n] =
                        tanhf(acc[mi][ni][j] + bv);
                }
        }
        return;
    }

    // ---- L1 epilogue: relu -> bf16 -> hid LDS (XOR-swizzled chunks) ----
    #pragma unroll
    for (int ni = 0; ni < 4; ni++) {
        const int n  = wn + ni * 16 + ln15;
        const float bv = b1[n];
        const int c8 = n >> 3;
        const int cl = (n & 7) * 2;
        #pragma unroll
        for (int mi = 0; mi < 4; mi++)
            #pragma unroll
            for (int j = 0; j < 4; j++) {
                const int r = mi * 16 + kq * 4 + j;
                float v = acc[mi][ni][j] + bv;
                v = v > 0.f ? v : 0.f;
                *(unsigned short*)((char*)hid + r * 1024 +
                                   ((c8 ^ (r & 7)) * 16) + cl) = f2bf(v);
            }
    }
    #pragma unroll
    for (int mi = 0; mi < 4; mi++)
        #pragma unroll
        for (int ni = 0; ni < 4; ni++)
            acc[mi][ni] = f32x4{0.f, 0.f, 0.f, 0.f};
    __syncthreads();                       // hid visible (full drain, once)

    // ---- L2: acc = hid[64,512] @ W2[512,512], A from LDS, B reg-dbuf ----
    LOADB(bA, W2T, 0);
    for (int t2 = 0; t2 < 16; t2 += 2) {
        bf16x8 af[4];
        LOADB(bB, W2T, (t2 + 1) * 32);
        #pragma unroll
        for (int mi = 0; mi < 4; mi++) {
            const int r = mi * 16 + ln15;
            const int c8 = t2 * 4 + kq;
            af[mi] = *(const bf16x8*)((char*)hid + r * 1024 +
                                      ((c8 ^ (r & 7)) * 16));
        }
        MMAC(bA, af);
        if (t2 + 2 < 16) { LOADB(bA, W2T, (t2 + 2) * 32); }
        #pragma unroll
        for (int mi = 0; mi < 4; mi++) {
            const int r = mi * 16 + ln15;
            const int c8 = (t2 + 1) * 4 + kq;
            af[mi] = *(const bf16x8*)((char*)hid + r * 1024 +
                                      ((c8 ^ (r & 7)) * 16));
        }
        MMAC(bB, af);
    }

    // ---- L2 epilogue: +bias -> fp32 out ----
    #pragma unroll
    for (int ni = 0; ni < 4; ni++) {
        const int n  = wn + ni * 16 + ln15;
        const float bv = b2[n];
        #pragma unroll
        for (int mi = 0; mi < 4; mi++)
            #pragma unroll
            for (int j = 0; j < 4; j++) {
                const int r = mi * 16 + kq * 4 + j;
                const int m = m0 + r;
                const int b = m / P, p = m % P;    // P constexpr -> shifts
                out[((size_t)b * 40 + QBASE + p) * 512 + n] =
                    acc[mi][ni][j] + bv;
            }
    }
}

// ---------- fused phase kernel ----------
struct FArgs {
    const unsigned short *and_At, *or_At, *not_At;
    const unsigned short *and_W1T, *and_W2T, *or_W1T, *or_W2T, *not_WT;
    const int *not_idx, *leftover;
    const float *and_b1, *and_b2, *or_b1, *or_b2, *not_b;
    float* out;
};

__global__ __launch_bounds__(512, 4) void fused_phase(FArgs a) {
    __shared__ __align__(16) unsigned short As[4 * 64 * 32];   // 16 KB, 4 bufs
    __shared__ __align__(16) unsigned short hid[64 * 512];     // 64 KB
    const int blk = blockIdx.x;
    if (blk < 256)        // and: M=16384 -> 256 blocks of 64 rows
        fused_seg<16, 1024, 0, 0>(a.and_At, a.and_W1T, a.and_b1,
                                  a.and_W2T, a.and_b2, a.out,
                                  nullptr, nullptr, blk, As, hid);
    else if (blk < 384)   // or: M=8192 -> 128 blocks
        fused_seg<8, 1024, 0, 16>(a.or_At, a.or_W1T, a.or_b1,
                                  a.or_W2T, a.or_b2, a.out,
                                  nullptr, nullptr, blk - 256, As, hid);
    else                  // not: M=8192, single layer tanh -> 128 blocks
        fused_seg<8, 512, 2, 24>(a.not_At, a.not_WT, a.not_b,
                                 nullptr, nullptr, a.out,
                                 a.not_idx, a.leftover, blk - 384, As, hid);
}

// ---------- launch ----------
extern "C" void kernel_launch(void* const* d_in, const int* in_sizes, int n_in,
                              void* d_out, int out_size, void* d_ws, size_t ws_size,
                              hipStream_t stream) {
    const float* fv       = (const float*)d_in[0];
    const float* and_W1   = (const float*)d_in[1];
    const float* and_b1   = (const float*)d_in[2];
    const float* and_W2   = (const float*)d_in[3];
    const float* and_b2   = (const float*)d_in[4];
    const float* or_W1    = (const float*)d_in[5];
    const float* or_b1    = (const float*)d_in[6];
    const float* or_W2    = (const float*)d_in[7];
    const float* or_b2    = (const float*)d_in[8];
    const float* not_W    = (const float*)d_in[9];
    const float* not_b    = (const float*)d_in[10];
    const int* not_idx    = (const int*)d_in[11];
    const int* and_pairs  = (const int*)d_in[12];
    const int* or_pairs   = (const int*)d_in[13];
    const int* leftover   = (const int*)d_in[14];
    float* out = (float*)d_out;
    char* ws = (char*)d_ws;

    // ws layout (bytes)
    unsigned short* and_At  = (unsigned short*)(ws);              // 32 MB
    unsigned short* or_At   = (unsigned short*)(ws + 33554432);   // 16 MB
    unsigned short* not_At  = (unsigned short*)(ws + 50331648);   // 8 MB
    unsigned short* and_W1T = (unsigned short*)(ws + 58720256);   // 1 MB
    unsigned short* or_W1T  = (unsigned short*)(ws + 59768832);   // 1 MB
    unsigned short* and_W2T = (unsigned short*)(ws + 60817408);   // 0.5 MB
    unsigned short* or_W2T  = (unsigned short*)(ws + 61341696);   // 0.5 MB
    unsigned short* not_WT  = (unsigned short*)(ws + 61865984);   // 0.5 MB

    PrepArgs pa;
    pa.fv = fv; pa.out = out;
    pa.and_At = and_At; pa.or_At = or_At; pa.not_At = not_At;
    pa.and_pairs = and_pairs; pa.or_pairs = or_pairs;
    pa.not_idx = not_idx; pa.lidx = leftover;
    pa.W[0] = and_W1; pa.WT[0] = and_W1T; pa.N[0] = 512;
    pa.W[1] = or_W1;  pa.WT[1] = or_W1T;  pa.N[1] = 512;
    pa.W[2] = and_W2; pa.WT[2] = and_W2T; pa.N[2] = 512;
    pa.W[3] = or_W2;  pa.WT[3] = or_W2T;  pa.N[3] = 512;
    pa.W[4] = not_W;  pa.WT[4] = not_WT;  pa.N[4] = 512;
    pa.tstart[0] = 0;   pa.tstart[1] = 128; pa.tstart[2] = 256;
    pa.tstart[3] = 320; pa.tstart[4] = 384; pa.tstart[5] = 448;
    prep_kernel<<<dim3(448 + 16384), dim3(256), 0, stream>>>(pa);

    FArgs fa;
    fa.and_At = and_At; fa.or_At = or_At; fa.not_At = not_At;
    fa.and_W1T = and_W1T; fa.and_W2T = and_W2T;
    fa.or_W1T = or_W1T;   fa.or_W2T = or_W2T;   fa.not_WT = not_WT;
    fa.not_idx = not_idx; fa.leftover = leftover;
    fa.and_b1 = and_b1; fa.and_b2 = and_b2;
    fa.or_b1 = or_b1;   fa.or_b2 = or_b2;   fa.not_b = not_b;
    fa.out = out;
    fused_phase<<<dim3(512), dim3(512), 0, stream>>>(fa);
}